// Round 8
// baseline (255.218 us; speedup 1.0000x reference)
//
#include <hip/hip_runtime.h>
#include <stdint.h>

#define SEQ   2048
#define DIM   1024
#define BATCH 4

typedef _Float16 f16;
typedef __attribute__((ext_vector_type(8))) _Float16 f16x8;
typedef __attribute__((ext_vector_type(4))) _Float16 f16x4;
typedef __attribute__((ext_vector_type(4))) float   f32x4;

typedef void __attribute__((address_space(1))) vg_t;
typedef void __attribute__((address_space(3))) vl_t;

__device__ __forceinline__ void gld16(const void* g, void* l) {
  // async global->LDS, 16B per lane; LDS dest = wave-uniform base + lane*16
  __builtin_amdgcn_global_load_lds((vg_t*)g, (vl_t*)l, 16, 0, 0);
}

// ---------------------------------------------------------------------------
// fp32->fp16 convert of Wq|Wk|Wv only (3 MB). x is no longer pre-converted:
// the QKV GEMM reg-stages A from f32 directly (kills x's 50 MB round-trip:
// 33.5 MB f32 read + 16.8 MB f16 write + 16.8 MB re-read).
// ---------------------------------------------------------------------------
__global__ __launch_bounds__(256) void cvt_w(const float* __restrict__ wq,
                                             const float* __restrict__ wk,
                                             const float* __restrict__ wv,
                                             f16* __restrict__ wh) {
  const int bx = blockIdx.x;
  const float* in; int base;
  if (bx < 1024)      { in = wq; base = bx; }
  else if (bx < 2048) { in = wk; base = bx - 1024; }
  else                { in = wv; base = bx - 2048; }
  f16* out = wh + ((size_t)(bx >> 10) << 20);
  const long i = ((long)base * 256 + threadIdx.x) * 4;
  float4 v = *(const float4*)(in + i);
  f16x4 o = { (f16)v.x, (f16)v.y, (f16)v.z, (f16)v.w };
  *(f16x4*)(out + i) = o;
}

// ---------------------------------------------------------------------------
// Fused QKV GEMM with in-register f32->f16 A conversion.
// Structure = the proven 67.2us gemm_bt<3,0,64> (128x128 tile, 4 waves,
// 16x16x32 MFMA, BK=64, grid (64,24) -> 6 blocks/CU; r7 proved this kernel's
// throughput is TLP-carried: 3 blocks/CU dropped MfmaUtil 32->20%).
// ONLY change: A staged from f32 x via regs (2x float4 per lane per
// wave-load, convert, ds_write_b128) to the EXACT linear LDS slots gld16
// used (lane*16B -> conflict-free writes; read side byte-identical).
// Source chunk = (lane&7) ^ (row&7) keeps the XOR swizzle (rule 21).
// A-panel re-reads are XCD-local for free: gridDim.x=64 == 0 mod 8, so all
// 24 n-blocks of an m-panel share bx%8 -> same XCD's L2.
// ---------------------------------------------------------------------------
__global__ __launch_bounds__(256) void qkv_gemm(const float* __restrict__ X,
                                                const f16* __restrict__ Wh,
                                                f16* __restrict__ Qh) {
  constexpr int BK = 64, CH = 8;
  __shared__ __align__(16) f16 lA[128 * BK];
  __shared__ __align__(16) f16 lB[128 * BK];

  const int tid  = threadIdx.x;
  const int wave = tid >> 6;
  const int lane = tid & 63;
  const int m0 = blockIdx.x * 128;
  const int n0 = blockIdx.y * 128;

  const float* Ab = X  + (long)m0 * DIM;
  const f16*   Bb = Wh + (long)n0 * DIM;

  const int wm = (wave & 1) * 64;
  const int wn = (wave >> 1) * 64;

  f32x4 acc[4][4] = {};

  const int srow = lane >> 3;          // B staging: 8 rows per wave-load
  const int sj   = lane & 7;
  const int fr   = lane & 15;
  const int fq   = lane >> 4;
  // A reg-staging: dest slot rgrp*512 + lane*8 (f16) == row rgrp*8 + (lane>>3),
  // chunk lane&7; source chunk = (lane&7) ^ (row&7), row&7 == lane>>3.
  const int agch = (lane & 7) ^ (lane >> 3);

  for (int kt = 0; kt < DIM; kt += BK) {
    // issue A f32 loads before the barrier (no LDS touched; latency hides
    // under the barrier + B-issue window)
    float4 av[4][2];
#pragma unroll
    for (int j = 0; j < 4; ++j) {
      const int rgrp = j * 4 + wave;
      const int row  = rgrp * 8 + (lane >> 3);
      const float* src = Ab + (long)row * DIM + kt + agch * 8;
      av[j][0] = *(const float4*)(src);
      av[j][1] = *(const float4*)(src + 4);
    }
    __syncthreads();  // previous iteration's ds_reads done
#pragma unroll
    for (int j = 0; j < 4; ++j) {
      const int rgrp = j * 4 + wave;
      const int row  = rgrp * 8 + srow;
      const int gch  = sj ^ (row & 7);
      gld16(Bb + (long)row * DIM + kt + gch * 8, (void*)(lB + rgrp * 512 + lane * 8));
    }
#pragma unroll
    for (int j = 0; j < 4; ++j) {
      const int rgrp = j * 4 + wave;
      f16x8 o = { (f16)av[j][0].x, (f16)av[j][0].y, (f16)av[j][0].z, (f16)av[j][0].w,
                  (f16)av[j][1].x, (f16)av[j][1].y, (f16)av[j][1].z, (f16)av[j][1].w };
      *(f16x8*)(lA + rgrp * 512 + lane * 8) = o;   // linear dest, conflict-free
    }
    __syncthreads();  // vmcnt (B) + lgkm (A writes) drained -> staging visible

#pragma unroll
    for (int kk = 0; kk < BK; kk += 32) {
      f16x8 af[4], bf[4];
#pragma unroll
      for (int i = 0; i < 4; ++i) {
        const int arow = wm + i * 16 + fr;
        const int ach  = (kk / 8 + fq) ^ (arow & (CH - 1));
        af[i] = *(const f16x8*)(lA + arow * BK + ach * 8);
        const int brow = wn + i * 16 + fr;
        const int bch  = (kk / 8 + fq) ^ (brow & (CH - 1));
        bf[i] = *(const f16x8*)(lB + brow * BK + bch * 8);
      }
#pragma unroll
      for (int mi = 0; mi < 4; ++mi)
#pragma unroll
        for (int ni = 0; ni < 4; ++ni)
          acc[mi][ni] = __builtin_amdgcn_mfma_f32_16x16x32_f16(af[mi], bf[ni], acc[mi][ni], 0, 0, 0);
    }
  }

  // Epilogue: fused QKV routing. C/D: col = lane&15, row = (lane>>4)*4 + reg
  f16* Kh  = Qh + (size_t)8 * 1024 * 1024;
  f16* VTb = Kh + (size_t)8 * 1024 * 1024;
#pragma unroll
  for (int mi = 0; mi < 4; ++mi) {
    const int row = m0 + wm + mi * 16 + fq * 4;
#pragma unroll
    for (int ni = 0; ni < 4; ++ni) {
      const int col = n0 + wn + ni * 16 + fr;
      if (col < 1024) {
#pragma unroll
        for (int r = 0; r < 4; ++r) Qh[(long)(row + r) * DIM + col] = (f16)acc[mi][ni][r];
      } else if (col < 2048) {
#pragma unroll
        for (int r = 0; r < 4; ++r) Kh[(long)(row + r) * DIM + (col - 1024)] = (f16)acc[mi][ni][r];
      } else {
        f16x4 o = { (f16)acc[mi][ni][0], (f16)acc[mi][ni][1],
                    (f16)acc[mi][ni][2], (f16)acc[mi][ni][3] };
        *(f16x4*)(VTb + (long)(col - 2048) * (BATCH * SEQ) + row) = o;
      }
    }
  }
}

// ---------------------------------------------------------------------------
// NT GEMM (used for PV only): C[m,n] = sum_k A[m,k]*B[n,k], fp16 in, fp32 acc.
// 128x128 tile, 4 waves, 16x16x32 MFMA, BK template.
// MODE: 0 fp32 row-major, 1 fp16 row-major, 2 fp16 transposed.
// CAUSAL: 2 K-limit m0+128; 3 = PV balanced 1D grid (512 blocks):
// anti-symmetric longest<->shortest pairing -> per-CU Keff-sum constant.
// ---------------------------------------------------------------------------
template <int MODE, int CAUSAL, int BK>
__global__ __launch_bounds__(256) void gemm_bt(const f16* __restrict__ A, int lda, long aOffZ,
                                               const f16* __restrict__ B, int ldb, long bOffZ,
                                               void* __restrict__ Cv, int ldc, long cOffZ,
                                               int K) {
  constexpr int CH  = BK / 8;
  constexpr int RPL = 64 / CH;
  constexpr int NL  = 32 / RPL;
  __shared__ __align__(16) f16 lA[128 * BK];
  __shared__ __align__(16) f16 lB[128 * BK];

  const int tid  = threadIdx.x;
  const int wave = tid >> 6;
  const int lane = tid & 63;

  int m0, n0, z;
  if (CAUSAL == 3) {
    const int id   = blockIdx.x;
    const int item = (id < 256) ? id : 767 - id;
    const int mt   = 15 - (item >> 5);
    const int j    = item & 31;
    m0 = mt * 128;
    n0 = (j & 7) * 128;
    z  = j >> 3;
  } else {
    m0 = blockIdx.x * 128;
    n0 = blockIdx.y * 128;
    z  = blockIdx.z;
  }

  if (CAUSAL == 1 && n0 >= m0 + 128) return;
  const int Keff = (CAUSAL >= 2) ? (m0 + 128) : K;

  const f16* Ab = A + (long)z * aOffZ + (long)m0 * lda;
  const f16* Bb = B + (long)z * bOffZ + (long)n0 * ldb;

  const int wm = (wave & 1) * 64;
  const int wn = (wave >> 1) * 64;

  f32x4 acc[4][4] = {};

  const int srow = lane / CH;
  const int sj   = lane % CH;
  const int fr   = lane & 15;
  const int fq   = lane >> 4;

  for (int kt = 0; kt < Keff; kt += BK) {
    __syncthreads();
#pragma unroll
    for (int j = 0; j < NL; ++j) {
      const int rgrp = j * 4 + wave;
      const int row  = rgrp * RPL + srow;
      const int gch  = sj ^ (row & (CH - 1));
      gld16(Ab + (long)row * lda + kt + gch * 8, (void*)(lA + rgrp * 512 + lane * 8));
      gld16(Bb + (long)row * ldb + kt + gch * 8, (void*)(lB + rgrp * 512 + lane * 8));
    }
    __syncthreads();

#pragma unroll
    for (int kk = 0; kk < BK; kk += 32) {
      f16x8 af[4], bf[4];
#pragma unroll
      for (int i = 0; i < 4; ++i) {
        const int arow = wm + i * 16 + fr;
        const int ach  = (kk / 8 + fq) ^ (arow & (CH - 1));
        af[i] = *(const f16x8*)(lA + arow * BK + ach * 8);
        const int brow = wn + i * 16 + fr;
        const int bch  = (kk / 8 + fq) ^ (brow & (CH - 1));
        bf[i] = *(const f16x8*)(lB + brow * BK + bch * 8);
      }
#pragma unroll
      for (int mi = 0; mi < 4; ++mi)
#pragma unroll
        for (int ni = 0; ni < 4; ++ni)
          acc[mi][ni] = __builtin_amdgcn_mfma_f32_16x16x32_f16(af[mi], bf[ni], acc[mi][ni], 0, 0, 0);
    }
  }

  // Epilogue. C/D layout: col = lane&15, row = (lane>>4)*4 + reg
#pragma unroll
  for (int mi = 0; mi < 4; ++mi) {
    const int row = m0 + wm + mi * 16 + fq * 4;
#pragma unroll
    for (int ni = 0; ni < 4; ++ni) {
      const int col = n0 + wn + ni * 16 + fr;
      if constexpr (MODE == 0) {
        float* C = (float*)Cv + (long)z * cOffZ;
#pragma unroll
        for (int r = 0; r < 4; ++r) C[(long)(row + r) * ldc + col] = acc[mi][ni][r];
      } else if constexpr (MODE == 1) {
        f16* C = (f16*)Cv + (long)z * cOffZ;
#pragma unroll
        for (int r = 0; r < 4; ++r) C[(long)(row + r) * ldc + col] = (f16)acc[mi][ni][r];
      } else {  // MODE 2
        f16* C = (f16*)Cv + (long)z * cOffZ;
        f16x4 o = { (f16)acc[mi][ni][0], (f16)acc[mi][ni][1],
                    (f16)acc[mi][ni][2], (f16)acc[mi][ni][3] };
        *(f16x4*)(C + (long)col * ldc + row) = o;
      }
    }
  }
}

// ---------------------------------------------------------------------------
// scores = Q K^T, causal, 128(M) x 96(N) tiles, BK=128, f16 out.
// 748-block compact causal grid (2.92/CU). Unchanged (control).
// ---------------------------------------------------------------------------
__global__ __launch_bounds__(256) void scores_96(const f16* __restrict__ Qh,
                                                 const f16* __restrict__ Kh,
                                                 f16* __restrict__ Sc) {
  __shared__ __align__(16) f16 lA[128 * 128];
  __shared__ __align__(16) f16 lB[96 * 128];

  const int tid  = threadIdx.x;
  const int wave = tid >> 6;
  const int lane = tid & 63;
  const int srow = lane >> 4;
  const int sj   = lane & 15;
  const int fr   = lane & 15;
  const int fq   = lane >> 4;
  const int wm   = (wave & 1) * 64;
  const int wn   = (wave >> 1) * 48;

  const int b = blockIdx.x;
  const int z = b / 187;
  int rem = b - z * 187;
  int mt = 0;
  while (true) {
    const int c = (128 * mt + 127) / 96 + 1;
    if (rem < c) break;
    rem -= c;
    ++mt;
  }
  const int m0 = mt * 128;
  const int n0 = rem * 96;

  const f16* Ab = Qh + (long)z * (SEQ * DIM) + (long)m0 * DIM;
  const f16* Bb = Kh + (long)z * (SEQ * DIM) + (long)n0 * DIM;

  f32x4 acc[4][3] = {};

  for (int kt = 0; kt < DIM; kt += 128) {
    __syncthreads();
#pragma unroll
    for (int j = 0; j < 8; ++j) {
      const int rgrp = j * 4 + wave;
      const int row  = rgrp * 4 + srow;
      const int gch  = sj ^ (row & 15);
      gld16(Ab + (long)row * DIM + kt + gch * 8, (void*)(lA + rgrp * 512 + lane * 8));
    }
#pragma unroll
    for (int j = 0; j < 6; ++j) {
      const int rgrp = j * 4 + wave;
      const int row  = rgrp * 4 + srow;
      const int gch  = sj ^ (row & 15);
      gld16(Bb + (long)row * DIM + kt + gch * 8, (void*)(lB + rgrp * 512 + lane * 8));
    }
    __syncthreads();

#pragma unroll
    for (int kk = 0; kk < 128; kk += 32) {
      f16x8 af[4], bf[3];
#pragma unroll
      for (int i = 0; i < 4; ++i) {
        const int arow = wm + i * 16 + fr;
        const int ach  = (kk / 8 + fq) ^ (arow & 15);
        af[i] = *(const f16x8*)(lA + arow * 128 + ach * 8);
      }
#pragma unroll
      for (int i = 0; i < 3; ++i) {
        const int brow = wn + i * 16 + fr;
        const int bch  = (kk / 8 + fq) ^ (brow & 15);
        bf[i] = *(const f16x8*)(lB + brow * 128 + bch * 8);
      }
#pragma unroll
      for (int mi = 0; mi < 4; ++mi)
#pragma unroll
        for (int ni = 0; ni < 3; ++ni)
          acc[mi][ni] = __builtin_amdgcn_mfma_f32_16x16x32_f16(af[mi], bf[ni], acc[mi][ni], 0, 0, 0);
    }
  }

  f16* C = Sc + (long)z * SEQ * SEQ;
#pragma unroll
  for (int mi = 0; mi < 4; ++mi) {
    const int row = m0 + wm + mi * 16 + fq * 4;
#pragma unroll
    for (int ni = 0; ni < 3; ++ni) {
      const int col = n0 + wn + ni * 16 + fr;
      if (col < SEQ) {
#pragma unroll
        for (int r = 0; r < 4; ++r)
          C[(long)(row + r) * SEQ + col] = (f16)acc[mi][ni][r];
      }
    }
  }
}

// ---------------------------------------------------------------------------
// Causal softmax over f16 score rows, in-place (zero above diagonal).
// Loads skipped above the diagonal; writes only the ceil((q+1)/128)*128 cols
// PV reads. Unchanged (control).
// ---------------------------------------------------------------------------
__global__ __launch_bounds__(256) void softmax_causal(f16* S) {
  const int q = blockIdx.x, b = blockIdx.y;
  f16* row = S + ((long)b * SEQ + q) * SEQ;
  const int tid = threadIdx.x;
  const int lane = tid & 63, wave = tid >> 6;
  const int nvalid = q + 1;
  const int kneed  = ((q >> 7) + 1) << 7;

  f16x8 vv = {};
  if (tid * 8 < nvalid) vv = *(const f16x8*)(row + tid * 8);
  float v[8];
  float m = -3.0e38f;
#pragma unroll
  for (int i = 0; i < 8; ++i) {
    const int k = tid * 8 + i;
    v[i] = (k < nvalid) ? (float)vv[i] * 0.03125f : -3.0e38f;
    m = fmaxf(m, v[i]);
  }
#pragma unroll
  for (int off = 32; off; off >>= 1) m = fmaxf(m, __shfl_xor(m, off));
  __shared__ float redm[4], reds[4];
  if (lane == 0) redm[wave] = m;
  __syncthreads();
  m = fmaxf(fmaxf(redm[0], redm[1]), fmaxf(redm[2], redm[3]));

  float s = 0.f;
#pragma unroll
  for (int i = 0; i < 8; ++i) {
    const float p = (v[i] > -1.0e37f) ? __expf(v[i] - m) : 0.f;
    v[i] = p;
    s += p;
  }
#pragma unroll
  for (int off = 32; off; off >>= 1) s += __shfl_xor(s, off);
  if (lane == 0) reds[wave] = s;
  __syncthreads();
  s = reds[0] + reds[1] + reds[2] + reds[3];
  const float inv = 1.f / s;
  f16x8 o;
#pragma unroll
  for (int i = 0; i < 8; ++i) o[i] = (f16)(v[i] * inv);
  if (tid * 8 < kneed) *(f16x8*)(row + tid * 8) = o;
}

// ---------------------------------------------------------------------------
extern "C" void kernel_launch(void* const* d_in, const int* in_sizes, int n_in,
                              void* d_out, int out_size, void* d_ws, size_t ws_size,
                              hipStream_t stream) {
  const float* x  = (const float*)d_in[0];
  const float* Wq = (const float*)d_in[1];
  const float* Wk = (const float*)d_in[2];
  const float* Wv = (const float*)d_in[3];
  float* out = (float*)d_out;

  // ws layout (f16 elems): xb 8M (now unused) | Wh 3M | Qh 8M | Kh 8M |
  //                        VT 8M ([1024][8192]) | Sc 16M (4 x 2048 x 2048)
  if (ws_size < (size_t)51 * 1024 * 1024 * 2) return;

  f16* xb = (f16*)d_ws;
  f16* Wh = xb + (size_t)8 * 1024 * 1024;
  f16* Qh = Wh + (size_t)3 * 1024 * 1024;
  f16* Kh = Qh + (size_t)8 * 1024 * 1024;
  f16* VT = Kh + (size_t)8 * 1024 * 1024;
  f16* Sc = VT + (size_t)8 * 1024 * 1024;

  const long SOFF = (long)SEQ * SEQ;  // per-batch score offset (f16 elems)

  // weights only: 3 MB (x conversion is fused into qkv_gemm's A-staging)
  cvt_w<<<3072, 256, 0, stream>>>(Wq, Wk, Wv, Wh);

  // Fused QKV: M=8192, N=3072, K=1024. Single dispatch (r7: splitting cost
  // 28us -- throughput is TLP-carried, 6 blocks/CU required). A from f32 x.
  qkv_gemm<<<dim3(64, 24, 1), 256, 0, stream>>>(x, Wh, Qh);

  // scores = Q K^T (causal), 128x96 tiles, compact 748-block grid
  scores_96<<<748, 256, 0, stream>>>(Qh, Kh, Sc);

  // causal softmax (scale 1/32), in-place f16 probs
  softmax_causal<<<dim3(SEQ, BATCH), 256, 0, stream>>>(Sc);

  // Z = P V, BK=128 + balanced 1D grid
  gemm_bt<0, 3, 128><<<dim3(512, 1, 1), 256, 0, stream>>>(Sc, SEQ, SOFF,
                                                          VT, BATCH * SEQ, SEQ,
                                                          out, DIM, (long)SEQ * DIM, SEQ);
}

// Round 9
// 238.858 us; speedup vs baseline: 1.0685x; 1.0685x over previous
//
#include <hip/hip_runtime.h>
#include <stdint.h>

#define SEQ   2048
#define DIM   1024
#define BATCH 4

typedef _Float16 f16;
typedef __attribute__((ext_vector_type(8))) _Float16 f16x8;
typedef __attribute__((ext_vector_type(4))) _Float16 f16x4;
typedef __attribute__((ext_vector_type(4))) float   f32x4;

typedef void __attribute__((address_space(1))) vg_t;
typedef void __attribute__((address_space(3))) vl_t;

__device__ __forceinline__ void gld16(const void* g, void* l) {
  // async global->LDS, 16B per lane; LDS dest = wave-uniform base + lane*16
  __builtin_amdgcn_global_load_lds((vg_t*)g, (vl_t*)l, 16, 0, 0);
}

// ---------------------------------------------------------------------------
// Fused fp32->fp16 convert of x, Wq, Wk, Wv in ONE dispatch. (r8 lesson: do
// NOT fuse x-conversion into the GEMM -- f32 A panels are 4 MB/XCD = the
// whole L2, so A re-reads fall out of cache: FETCH +34 MB, qkv 67->97 us.)
// ---------------------------------------------------------------------------
__global__ __launch_bounds__(256) void cvt_all(const float* __restrict__ x,
                                               const float* __restrict__ wq,
                                               const float* __restrict__ wk,
                                               const float* __restrict__ wv,
                                               f16* __restrict__ xb,
                                               f16* __restrict__ wh) {
  const int bx = blockIdx.x;
  const float* in; f16* out; int base;
  if (bx < 8192)       { in = x;  out = xb;             base = bx; }
  else if (bx < 9216)  { in = wq; out = wh;             base = bx - 8192; }
  else if (bx < 10240) { in = wk; out = wh + (1 << 20); base = bx - 9216; }
  else                 { in = wv; out = wh + (2 << 20); base = bx - 10240; }
  const long i = ((long)base * 256 + threadIdx.x) * 4;
  float4 v = *(const float4*)(in + i);
  f16x4 o = { (f16)v.x, (f16)v.y, (f16)v.z, (f16)v.w };
  *(f16x4*)(out + i) = o;
}

// ---------------------------------------------------------------------------
// QKV NT GEMM (proven 67.2us config): 128x128 tile, 4 waves, 16x16x32 MFMA,
// BK=64 -> 32 KiB LDS, 6 blocks/CU (r7: throughput is TLP-carried).
// MODE 3 epilogue: Q/K row-major f16, V transposed [p][B*S].
// ---------------------------------------------------------------------------
template <int MODE, int CAUSAL, int BK>
__global__ __launch_bounds__(256) void gemm_bt(const f16* __restrict__ A, int lda, long aOffZ,
                                               const f16* __restrict__ B, int ldb, long bOffZ,
                                               void* __restrict__ Cv, int ldc, long cOffZ,
                                               int K) {
  constexpr int CH  = BK / 8;
  constexpr int RPL = 64 / CH;
  constexpr int NL  = 32 / RPL;
  __shared__ __align__(16) f16 lA[128 * BK];
  __shared__ __align__(16) f16 lB[128 * BK];

  const int tid  = threadIdx.x;
  const int wave = tid >> 6;
  const int lane = tid & 63;

  const int m0 = blockIdx.x * 128;
  const int n0 = blockIdx.y * 128;
  const int z  = blockIdx.z;
  const int Keff = K;

  const f16* Ab = A + (long)z * aOffZ + (long)m0 * lda;
  const f16* Bb = B + (long)z * bOffZ + (long)n0 * ldb;

  const int wm = (wave & 1) * 64;
  const int wn = (wave >> 1) * 64;

  f32x4 acc[4][4] = {};

  const int srow = lane / CH;
  const int sj   = lane % CH;
  const int fr   = lane & 15;
  const int fq   = lane >> 4;

  for (int kt = 0; kt < Keff; kt += BK) {
    __syncthreads();
#pragma unroll
    for (int j = 0; j < NL; ++j) {
      const int rgrp = j * 4 + wave;
      const int row  = rgrp * RPL + srow;
      const int gch  = sj ^ (row & (CH - 1));
      gld16(Ab + (long)row * lda + kt + gch * 8, (void*)(lA + rgrp * 512 + lane * 8));
      gld16(Bb + (long)row * ldb + kt + gch * 8, (void*)(lB + rgrp * 512 + lane * 8));
    }
    __syncthreads();

#pragma unroll
    for (int kk = 0; kk < BK; kk += 32) {
      f16x8 af[4], bf[4];
#pragma unroll
      for (int i = 0; i < 4; ++i) {
        const int arow = wm + i * 16 + fr;
        const int ach  = (kk / 8 + fq) ^ (arow & (CH - 1));
        af[i] = *(const f16x8*)(lA + arow * BK + ach * 8);
        const int brow = wn + i * 16 + fr;
        const int bch  = (kk / 8 + fq) ^ (brow & (CH - 1));
        bf[i] = *(const f16x8*)(lB + brow * BK + bch * 8);
      }
#pragma unroll
      for (int mi = 0; mi < 4; ++mi)
#pragma unroll
        for (int ni = 0; ni < 4; ++ni)
          acc[mi][ni] = __builtin_amdgcn_mfma_f32_16x16x32_f16(af[mi], bf[ni], acc[mi][ni], 0, 0, 0);
    }
  }

  // Epilogue. C/D layout: col = lane&15, row = (lane>>4)*4 + reg
#pragma unroll
  for (int mi = 0; mi < 4; ++mi) {
    const int row = m0 + wm + mi * 16 + fq * 4;
#pragma unroll
    for (int ni = 0; ni < 4; ++ni) {
      const int col = n0 + wn + ni * 16 + fr;
      if constexpr (MODE == 3) {  // fused QKV routing (wave-uniform regions)
        f16* Qh  = (f16*)Cv;
        f16* Kh  = Qh + (size_t)8 * 1024 * 1024;
        f16* VTb = Kh + (size_t)8 * 1024 * 1024;
        if (col < 1024) {
#pragma unroll
          for (int r = 0; r < 4; ++r) Qh[(long)(row + r) * DIM + col] = (f16)acc[mi][ni][r];
        } else if (col < 2048) {
#pragma unroll
          for (int r = 0; r < 4; ++r) Kh[(long)(row + r) * DIM + (col - 1024)] = (f16)acc[mi][ni][r];
        } else {
          f16x4 o = { (f16)acc[mi][ni][0], (f16)acc[mi][ni][1],
                      (f16)acc[mi][ni][2], (f16)acc[mi][ni][3] };
          *(f16x4*)(VTb + (long)(col - 2048) * (BATCH * SEQ) + row) = o;
        }
      } else {  // MODE 0: fp32 row-major (unused path kept for completeness)
        float* C = (float*)Cv + (long)z * cOffZ;
#pragma unroll
        for (int r = 0; r < 4; ++r) C[(long)(row + r) * ldc + col] = acc[mi][ni][r];
      }
    }
  }
}

// ---------------------------------------------------------------------------
// 64(M) x 128(N) tile GEMM, BK=64, 24 KB LDS -> 6 resident blocks/CU.
// r7's key finding: the 2-barrier structure's throughput is TLP-carried
// (QKV at 3 blocks/CU lost 1.4x). scores_96 (56 KB) and PV BK=128 (64 KB)
// both ran at 2 blocks/CU -- this kernel fixes exactly that.
// 4 waves as 2x2 -> wave 32x64, acc 2x4. Per-wave stage: A 2 + B 4 gld16.
// MODE 1 = scores: compact causal grid, 272 tiles/batch (m-tile mt has
//          (mt>>1)+1 n-tiles), 1088 blocks = 4.25/CU; f16 out; full K.
// MODE 0 = PV: 32 mt x 8 nt x 4 z = 1024 blocks = 4.0/CU; Keff = m0+64;
//          4-way anti-symmetric balance: CU c gets items {c, c+256, 1023-c,
//          767-c} -> Keff sum constant (round-robin pairing of same-Keff
//          blocks would give a 2x-work tail). fp32 out.
// ---------------------------------------------------------------------------
template <int MODE>
__global__ __launch_bounds__(256) void gemm64(const f16* __restrict__ A, int lda, long aOffZ,
                                              const f16* __restrict__ B, int ldb, long bOffZ,
                                              void* __restrict__ Cv, int ldc, long cOffZ,
                                              int K) {
  constexpr int BK = 64;
  __shared__ __align__(16) f16 lA[64 * BK];    //  8 KB
  __shared__ __align__(16) f16 lB[128 * BK];   // 16 KB

  const int tid  = threadIdx.x;
  const int wave = tid >> 6;
  const int lane = tid & 63;
  const int srow = lane >> 3;
  const int sj   = lane & 7;
  const int fr   = lane & 15;
  const int fq   = lane >> 4;
  const int wm   = (wave & 1) * 32;
  const int wn   = (wave >> 1) * 64;

  int m0, n0, z, Keff;
  if (MODE == 1) {                     // scores: compact causal decode
    const int b = blockIdx.x;
    z = b / 272;
    int rem = b - z * 272;
    int mt = 0;
    while (true) { const int c = (mt >> 1) + 1; if (rem < c) break; rem -= c; ++mt; }
    m0 = mt * 64; n0 = rem * 128; Keff = K;
  } else {                             // PV: balanced decode, 1024 blocks
    const int id   = blockIdx.x;
    const int item = (id < 512) ? id : 1535 - id;
    const int mt   = 31 - (item >> 5);
    const int j    = item & 31;
    m0 = mt * 64; n0 = (j & 7) * 128; z = j >> 3; Keff = m0 + 64;
  }

  const f16* Ab = A + (long)z * aOffZ + (long)m0 * lda;
  const f16* Bb = B + (long)z * bOffZ + (long)n0 * ldb;

  f32x4 acc[2][4] = {};

  for (int kt = 0; kt < Keff; kt += BK) {
    __syncthreads();
#pragma unroll
    for (int j = 0; j < 2; ++j) {      // A: 64 rows = 8 rgrps
      const int rgrp = j * 4 + wave;
      const int row  = rgrp * 8 + srow;
      const int gch  = sj ^ (row & 7);
      gld16(Ab + (long)row * lda + kt + gch * 8, (void*)(lA + rgrp * 512 + lane * 8));
    }
#pragma unroll
    for (int j = 0; j < 4; ++j) {      // B: 128 rows = 16 rgrps
      const int rgrp = j * 4 + wave;
      const int row  = rgrp * 8 + srow;
      const int gch  = sj ^ (row & 7);
      gld16(Bb + (long)row * ldb + kt + gch * 8, (void*)(lB + rgrp * 512 + lane * 8));
    }
    __syncthreads();

#pragma unroll
    for (int kk = 0; kk < BK; kk += 32) {
      f16x8 af[2], bf[4];
#pragma unroll
      for (int i = 0; i < 2; ++i) {
        const int arow = wm + i * 16 + fr;
        const int ach  = (kk / 8 + fq) ^ (arow & 7);
        af[i] = *(const f16x8*)(lA + arow * BK + ach * 8);
      }
#pragma unroll
      for (int i = 0; i < 4; ++i) {
        const int brow = wn + i * 16 + fr;
        const int bch  = (kk / 8 + fq) ^ (brow & 7);
        bf[i] = *(const f16x8*)(lB + brow * BK + bch * 8);
      }
#pragma unroll
      for (int mi = 0; mi < 2; ++mi)
#pragma unroll
        for (int ni = 0; ni < 4; ++ni)
          acc[mi][ni] = __builtin_amdgcn_mfma_f32_16x16x32_f16(af[mi], bf[ni], acc[mi][ni], 0, 0, 0);
    }
  }

  // Epilogue. C/D layout: col = lane&15, row = (lane>>4)*4 + reg
#pragma unroll
  for (int mi = 0; mi < 2; ++mi) {
    const int row = m0 + wm + mi * 16 + fq * 4;
#pragma unroll
    for (int ni = 0; ni < 4; ++ni) {
      const int col = n0 + wn + ni * 16 + fr;
      if constexpr (MODE == 1) {
        f16* C = (f16*)Cv + (long)z * cOffZ;
#pragma unroll
        for (int r = 0; r < 4; ++r) C[(long)(row + r) * ldc + col] = (f16)acc[mi][ni][r];
      } else {
        float* C = (float*)Cv + (long)z * cOffZ;
#pragma unroll
        for (int r = 0; r < 4; ++r) C[(long)(row + r) * ldc + col] = acc[mi][ni][r];
      }
    }
  }
}

// ---------------------------------------------------------------------------
// Causal softmax over f16 score rows, in-place (zero above diagonal).
// grid = (SEQ, BATCH), block = 256, 8 contiguous elems/thread (f16x8).
// Loads skipped above the diagonal; writes only the ceil((q+1)/64)*64 cols
// the 64-row-tile PV actually reads (Keff = m0+64).
// ---------------------------------------------------------------------------
__global__ __launch_bounds__(256) void softmax_causal(f16* S) {
  const int q = blockIdx.x, b = blockIdx.y;
  f16* row = S + ((long)b * SEQ + q) * SEQ;
  const int tid = threadIdx.x;
  const int lane = tid & 63, wave = tid >> 6;
  const int nvalid = q + 1;
  const int kneed  = ((q >> 6) + 1) << 6;  // 64-aligned: PV tile K-limit

  f16x8 vv = {};
  if (tid * 8 < nvalid) vv = *(const f16x8*)(row + tid * 8);
  float v[8];
  float m = -3.0e38f;
#pragma unroll
  for (int i = 0; i < 8; ++i) {
    const int k = tid * 8 + i;
    v[i] = (k < nvalid) ? (float)vv[i] * 0.03125f : -3.0e38f;
    m = fmaxf(m, v[i]);
  }
#pragma unroll
  for (int off = 32; off; off >>= 1) m = fmaxf(m, __shfl_xor(m, off));
  __shared__ float redm[4], reds[4];
  if (lane == 0) redm[wave] = m;
  __syncthreads();
  m = fmaxf(fmaxf(redm[0], redm[1]), fmaxf(redm[2], redm[3]));

  float s = 0.f;
#pragma unroll
  for (int i = 0; i < 8; ++i) {
    const float p = (v[i] > -1.0e37f) ? __expf(v[i] - m) : 0.f;
    v[i] = p;
    s += p;
  }
#pragma unroll
  for (int off = 32; off; off >>= 1) s += __shfl_xor(s, off);
  if (lane == 0) reds[wave] = s;
  __syncthreads();
  s = reds[0] + reds[1] + reds[2] + reds[3];
  const float inv = 1.f / s;
  f16x8 o;
#pragma unroll
  for (int i = 0; i < 8; ++i) o[i] = (f16)(v[i] * inv);
  if (tid * 8 < kneed) *(f16x8*)(row + tid * 8) = o;
}

// ---------------------------------------------------------------------------
extern "C" void kernel_launch(void* const* d_in, const int* in_sizes, int n_in,
                              void* d_out, int out_size, void* d_ws, size_t ws_size,
                              hipStream_t stream) {
  const float* x  = (const float*)d_in[0];
  const float* Wq = (const float*)d_in[1];
  const float* Wk = (const float*)d_in[2];
  const float* Wv = (const float*)d_in[3];
  float* out = (float*)d_out;

  // ws layout (f16 elems): xb 8M | Wh 3M | Qh 8M | Kh 8M | VT 8M ([1024][8192]) |
  //                        Sc 16M f16 scores->probs in place (4 x 2048 x 2048)
  if (ws_size < (size_t)51 * 1024 * 1024 * 2) return;

  f16* xb = (f16*)d_ws;
  f16* Wh = xb + (size_t)8 * 1024 * 1024;
  f16* Qh = Wh + (size_t)3 * 1024 * 1024;
  f16* Kh = Qh + (size_t)8 * 1024 * 1024;
  f16* VT = Kh + (size_t)8 * 1024 * 1024;
  f16* Sc = VT + (size_t)8 * 1024 * 1024;

  const long QOFF = (long)SEQ * DIM;  // per-batch Q/K offset
  const long SOFF = (long)SEQ * SEQ;  // per-batch score offset (f16 elems)

  cvt_all<<<11264, 256, 0, stream>>>(x, Wq, Wk, Wv, xb, Wh);

  // Fused QKV: M=8192, N=3072, K=1024. Proven config: 128x128/BK=64,
  // single dispatch, 6 blocks/CU.
  gemm_bt<3, 0, 64><<<dim3(64, 24, 1), 256, 0, stream>>>(xb, DIM, 0, Wh, DIM, 0, Qh, 0, 0, DIM);

  // scores = Q K^T (causal): 64x128 tiles, 1088 blocks = 4.25/CU, 24 KB LDS
  gemm64<1><<<1088, 256, 0, stream>>>(Qh, DIM, QOFF, Kh, DIM, QOFF,
                                      Sc, SEQ, SOFF, DIM);

  // causal softmax (scale 1/32), in-place f16 probs
  softmax_causal<<<dim3(SEQ, BATCH), 256, 0, stream>>>(Sc);

  // Z = P V: 64x128 tiles, 1024 blocks = 4/CU, Keff-balanced 4-way
  gemm64<0><<<1024, 256, 0, stream>>>(Sc, SEQ, SOFF, VT, BATCH * SEQ, SEQ,
                                      out, DIM, (long)SEQ * DIM, SEQ);
}